// Round 9
// baseline (188.280 us; speedup 1.0000x reference)
//
#include <hip/hip_runtime.h>
#include <hip/hip_bf16.h>
#include <cstdint>

#define B_  2
#define S_  2048
#define D_  1024
#define H_  16
#define HD_ 64
#define M_  (B_ * S_)   // 4096
static constexpr float SC_LOG2E = 0.125f * 1.44269504088896f;  // SCALE * log2(e), folded into Q

typedef __bf16 bf16x8 __attribute__((ext_vector_type(8)));
typedef __bf16 bf16x4 __attribute__((ext_vector_type(4)));
typedef float  f32x4  __attribute__((ext_vector_type(4)));

__device__ __forceinline__ unsigned short f2b(float f) {
  union { float f; unsigned u; } x; x.f = f;
  unsigned r = x.u + 0x7FFF + ((x.u >> 16) & 1);   // RNE
  return (unsigned short)(r >> 16);
}

// async global->LDS, 16B per lane; HW uses wave-uniform LDS base + lane*16
__device__ __forceinline__ void gl_lds16(const unsigned short* g, unsigned short* l) {
  __builtin_amdgcn_global_load_lds((const __attribute__((address_space(1))) void*)g,
                                   (__attribute__((address_space(3))) void*)l, 16, 0, 0);
}

// ------------------------------------------- fused cvt: z<4 -> transpose+cvt W, z==4 -> cvt x
__global__ void cvt_all_kernel(const float* __restrict__ x,
                               const float* __restrict__ w0, const float* __restrict__ w1,
                               const float* __restrict__ w2, const float* __restrict__ w3,
                               unsigned short* __restrict__ xb,
                               unsigned short* __restrict__ o0, unsigned short* __restrict__ o1,
                               unsigned short* __restrict__ o2, unsigned short* __restrict__ o3) {
  int tx = threadIdx.x, ty = threadIdx.y;
  if (blockIdx.z == 4) {
    int tid = ty * 32 + tx;
    int base = ((int)blockIdx.y * 32 + (int)blockIdx.x) * 1024 + tid;  // f4 index
    const float4* xf = (const float4*)x;
    ushort4* ob = (ushort4*)xb;
#pragma unroll
    for (int j = 0; j < 4; j++) {
      float4 v = xf[base + j * 256];
      ushort4 r;
      r.x = f2b(v.x); r.y = f2b(v.y); r.z = f2b(v.z); r.w = f2b(v.w);
      ob[base + j * 256] = r;
    }
    return;
  }
  const float* w = blockIdx.z == 0 ? w0 : blockIdx.z == 1 ? w1 : blockIdx.z == 2 ? w2 : w3;
  unsigned short* o = blockIdx.z == 0 ? o0 : blockIdx.z == 1 ? o1 : blockIdx.z == 2 ? o2 : o3;
  __shared__ float t[32][33];
  int x0 = blockIdx.x * 32, y0 = blockIdx.y * 32;
#pragma unroll
  for (int j = 0; j < 4; j++)
    t[ty + j * 8][tx] = w[(size_t)(y0 + ty + j * 8) * D_ + x0 + tx];
  __syncthreads();
#pragma unroll
  for (int j = 0; j < 4; j++)
    o[(size_t)(x0 + ty + j * 8) * D_ + y0 + tx] = f2b(t[tx][ty + j * 8]);
}

// ---------------------------------------------------------------- QKV GEMM
// 512 threads = 8 waves (2x4 wave grid, wave tile 64x32, acc[4][2]); 128x128 block tile,
// BK=32 dbuf staging with ONE barrier/iter; 1 A + 1 B gl_lds16 per thread per iter.
// z=0: Q*SC_LOG2E -> [B,H,S,HD]; z=1: K -> [B,H,S,HD]; z=2: V -> [B,H,HD,S] (transposed)
__global__ __launch_bounds__(512) void qkv_gemm_kernel(
    const unsigned short* __restrict__ xb,
    const unsigned short* __restrict__ wqt, const unsigned short* __restrict__ wkt,
    const unsigned short* __restrict__ wvt,
    const float* __restrict__ bq, const float* __restrict__ bk, const float* __restrict__ bv,
    unsigned short* __restrict__ qo, unsigned short* __restrict__ ko, unsigned short* __restrict__ vo) {
  const unsigned short* wt = blockIdx.z == 0 ? wqt : blockIdx.z == 1 ? wkt : wvt;
  const float* bias        = blockIdx.z == 0 ? bq  : blockIdx.z == 1 ? bk  : bv;
  unsigned short* out      = blockIdx.z == 0 ? qo  : blockIdx.z == 1 ? ko  : vo;
  const float scl = blockIdx.z == 0 ? SC_LOG2E : 1.0f;

  // As0 | As1 | Bs0 | Bs1 (each 128x32 bf16, unpadded for global_load_lds); offset
  // arithmetic (no LDS pointer arrays - addrspacecast static init is rejected).
  __shared__ __align__(16) unsigned short smem[4 * 128 * 32];   // 32 KB
  const int tid = threadIdx.x;
  const int lane = tid & 63, wid = tid >> 6;
  const int wm = wid & 1, wn = wid >> 1;          // 2 x 4 wave grid
  const int m0 = blockIdx.x * 128, n0 = blockIdx.y * 128;
  const int l15 = lane & 15, q4 = lane >> 4;
  const int srow = tid >> 2, skc = (tid & 3) * 8; // staging slot: 512 chunks, 1/thread

  f32x4 zero = {0.f, 0.f, 0.f, 0.f};
  f32x4 acc[4][2];
#pragma unroll
  for (int mt = 0; mt < 4; mt++)
#pragma unroll
    for (int nt = 0; nt < 2; nt++) acc[mt][nt] = zero;

  // preload tile 0 into buffer 0
  gl_lds16(xb + (size_t)(m0 + srow) * D_ + skc, smem + tid * 8);
  gl_lds16(wt + (size_t)(n0 + srow) * D_ + skc, smem + 8192 + tid * 8);

  int ib = 0;
  for (int kk = 0; kk < D_; kk += 32, ib ^= 1) {
    unsigned short* Ab = smem + ib * 4096;
    unsigned short* Bb = smem + 8192 + ib * 4096;
    unsigned short* An = smem + (ib ^ 1) * 4096;
    unsigned short* Bn = smem + 8192 + (ib ^ 1) * 4096;
    __syncthreads();                          // drains loads into buf ib; protects buf ib^1 reuse
    if (kk + 32 < D_) {
      gl_lds16(xb + (size_t)(m0 + srow) * D_ + kk + 32 + skc, An + tid * 8);
      gl_lds16(wt + (size_t)(n0 + srow) * D_ + kk + 32 + skc, Bn + tid * 8);
    }
    bf16x8 af[4], bfv[2];
#pragma unroll
    for (int mt = 0; mt < 4; mt++) af[mt]  = *(const bf16x8*)(Ab + (wm * 64 + mt * 16 + l15) * 32 + q4 * 8);
#pragma unroll
    for (int nt = 0; nt < 2; nt++) bfv[nt] = *(const bf16x8*)(Bb + (wn * 32 + nt * 16 + l15) * 32 + q4 * 8);
#pragma unroll
    for (int mt = 0; mt < 4; mt++)
#pragma unroll
      for (int nt = 0; nt < 2; nt++)
        acc[mt][nt] = __builtin_amdgcn_mfma_f32_16x16x32_bf16(af[mt], bfv[nt], acc[mt][nt], 0, 0, 0);
  }

  if (blockIdx.z < 2) {
    // Q/K: store [B,H,S,HD]
#pragma unroll
    for (int nt = 0; nt < 2; nt++) {
      int n = n0 + wn * 32 + nt * 16 + l15;
      float bn = bias[n];
      int h = n >> 6, hd = n & 63;
#pragma unroll
      for (int mt = 0; mt < 4; mt++) {
#pragma unroll
        for (int r = 0; r < 4; r++) {
          int m = m0 + wm * 64 + mt * 16 + q4 * 4 + r;   // C row = quad*4 + reg
          int b = m >> 11, s = m & (S_ - 1);
          out[(((size_t)(b * H_ + h)) * S_ + s) * HD_ + hd] = f2b((acc[mt][nt][r] + bn) * scl);
        }
      }
    }
  } else {
    // V: transpose via LDS (64x136 pad), store [B,H,HD,S] coalesced; packed b64 writes
    unsigned short* buf = smem;                         // 64*136 = 8704 shorts < 16384
#pragma unroll
    for (int p = 0; p < 2; p++) {                       // n-half: wn in {2p, 2p+1}
      __syncthreads();
      if ((wn >> 1) == p) {
#pragma unroll
        for (int nt = 0; nt < 2; nt++) {
          int np = (wn & 1) * 32 + nt * 16 + l15;       // n' in [0,64)
          float bn = bias[n0 + p * 64 + np];
#pragma unroll
          for (int mt = 0; mt < 4; mt++) {
            f32x4 vb = acc[mt][nt];
            vb[0] += bn; vb[1] += bn; vb[2] += bn; vb[3] += bn;
            bf16x4 pk = __builtin_convertvector(vb, bf16x4);
            *(bf16x4*)(&buf[np * 136 + wm * 64 + mt * 16 + q4 * 4]) = pk;
          }
        }
      }
      __syncthreads();
#pragma unroll
      for (int i = 0; i < 2; i++) {
        int ci = tid + i * 512;                      // 1024 chunks of 8
        int np = ci >> 4, c = ci & 15;
        int n = n0 + p * 64 + np;
        int h = n >> 6, hd = n & 63;
        int m = m0 + c * 8;
        int b = m >> 11, s = m & (S_ - 1);
        *(uint4*)(out + (((size_t)(b * H_ + h)) * HD_ + hd) * S_ + s) = *(const uint4*)(buf + np * 136 + c * 8);
      }
    }
  }
}

// ---------------------------------------------------------------- flash attention (S^T form)
// grid (8, B*H); 8 waves, 128 q-rows; block x does q-tiles {x, 15-x} (17 k-tiles, uniform).
// K/V SINGLE-buffered (LDS 69 KB -> 2 blocks/CU, 16 waves/CU); two barriers per tile but
// one block's barrier drain overlaps the other block's compute. Next-tile K/V held in regs
// across the stage-visible barrier (loads issued after it, full compute phase to land).
__global__ __launch_bounds__(512) void attn_kernel(
    const unsigned short* __restrict__ Q, const unsigned short* __restrict__ K,
    const unsigned short* __restrict__ Vt_g, unsigned short* __restrict__ O) {
  const int bh = blockIdx.y, b = bh >> 4, h = bh & 15;
  const unsigned short* Qh = Q    + (size_t)bh * S_ * HD_;
  const unsigned short* Kh = K    + (size_t)bh * S_ * HD_;
  const unsigned short* Vh = Vt_g + (size_t)bh * HD_ * S_;   // [HD][S]

  __shared__ __align__(16) unsigned short Ks[128 * 72];      // [key][hd], pad 72
  __shared__ __align__(16) unsigned short Vt[64 * 136];      // [hd][key], pad 136
  __shared__ __align__(16) unsigned short Ps[8][16 * 136];   // per-wave P [q][key]

  const int tid = threadIdx.x, lane = tid & 63, w = tid >> 6;
  const int l15 = lane & 15, q4 = lane >> 4;
  f32x4 zero = {0.f, 0.f, 0.f, 0.f};

  const int krow0 = tid >> 3, kcol0 = (tid & 7) * 8;          // K stage slots (this thread)
  const int vrow0 = tid >> 4, vcol0 = (tid & 15) * 8;         // Vt stage slots

  for (int half = 0; half < 2; half++) {
    const int qi = half ? (15 - (int)blockIdx.x) : (int)blockIdx.x;
    const int q0 = qi * 128;

    // Q B-frags direct from global: B[k=q4*8+j][n=l15] = Q[q0+w*16+l15][q4*8+j]
    const unsigned short* qp = Qh + (size_t)(q0 + w * 16 + l15) * HD_ + q4 * 8;
    bf16x8 bq0 = *(const bf16x8*)(qp);
    bf16x8 bq1 = *(const bf16x8*)(qp + 32);

    float m_i = -1e30f, l_i = 0.f;                 // state for q = q0 + w*16 + l15
    f32x4 o_acc[4];
#pragma unroll
    for (int t = 0; t < 4; t++) o_acc[t] = zero;
    const int qrow = q0 + w * 16 + l15;
    const int nkt = qi + 1;

    // prefetch tile 0 into regs
    uint4 kp0 = *(const uint4*)(Kh + (size_t)krow0 * HD_ + kcol0);
    uint4 kp1 = *(const uint4*)(Kh + (size_t)(krow0 + 64) * HD_ + kcol0);
    uint4 vp0 = *(const uint4*)(Vh + (size_t)vrow0 * S_ + vcol0);
    uint4 vp1 = *(const uint4*)(Vh + (size_t)(vrow0 + 32) * S_ + vcol0);

    for (int kt = 0; kt < nkt; kt++) {
      const int k0 = kt * 128;
      __syncthreads();                             // barrier A: prior tile's LDS reads done
      *(uint4*)(Ks + krow0 * 72 + kcol0) = kp0;
      *(uint4*)(Ks + (krow0 + 64) * 72 + kcol0) = kp1;
      *(uint4*)(Vt + vrow0 * 136 + vcol0) = vp0;
      *(uint4*)(Vt + (vrow0 + 32) * 136 + vcol0) = vp1;
      __syncthreads();                             // barrier B: staging visible
      if (kt + 1 < nkt) {                          // issue next-tile loads AFTER barrier
        int kn = k0 + 128;
        kp0 = *(const uint4*)(Kh + (size_t)(kn + krow0) * HD_ + kcol0);
        kp1 = *(const uint4*)(Kh + (size_t)(kn + krow0 + 64) * HD_ + kcol0);
        vp0 = *(const uint4*)(Vh + (size_t)vrow0 * S_ + kn + vcol0);
        vp1 = *(const uint4*)(Vh + (size_t)(vrow0 + 32) * S_ + kn + vcol0);
      }

      // S^T = K·Q^T : A = K-frag (m=key), B = Q-frag (n=q); Q pre-scaled by SC_LOG2E
      f32x4 sc[8];
#pragma unroll
      for (int nt = 0; nt < 8; nt++) sc[nt] = zero;
#pragma unroll
      for (int nt = 0; nt < 8; nt++) {
        bf16x8 ak0 = *(const bf16x8*)(Ks + (nt * 16 + l15) * 72 + q4 * 8);
        bf16x8 ak1 = *(const bf16x8*)(Ks + (nt * 16 + l15) * 72 + 32 + q4 * 8);
        sc[nt] = __builtin_amdgcn_mfma_f32_16x16x32_bf16(ak0, bq0, sc[nt], 0, 0, 0);
        sc[nt] = __builtin_amdgcn_mfma_f32_16x16x32_bf16(ak1, bq1, sc[nt], 0, 0, 0);
      }

      // softmax over keys for q = l15 (C layout: col=l15=q, row=q4*4+r=key), log2 domain
      const bool needMask = (k0 + 127) > (q0 + w * 16);
      float mx = m_i;
      if (needMask) {
#pragma unroll
        for (int nt = 0; nt < 8; nt++)
#pragma unroll
          for (int r = 0; r < 4; r++) {
            int key = k0 + nt * 16 + q4 * 4 + r;
            float v = (key > qrow) ? -1e30f : sc[nt][r];
            sc[nt][r] = v;
            mx = fmaxf(mx, v);
          }
      } else {
#pragma unroll
        for (int nt = 0; nt < 8; nt++)
#pragma unroll
          for (int r = 0; r < 4; r++) mx = fmaxf(mx, sc[nt][r]);
      }
      mx = fmaxf(mx, __shfl_xor(mx, 16));
      mx = fmaxf(mx, __shfl_xor(mx, 32));
      float alpha = __builtin_amdgcn_exp2f(m_i - mx);
      m_i = mx;
      float rs = 0.f;
#pragma unroll
      for (int nt = 0; nt < 8; nt++)
#pragma unroll
        for (int r = 0; r < 4; r++) {
          float p = __builtin_amdgcn_exp2f(sc[nt][r] - mx);
          sc[nt][r] = p;
          rs += p;
        }
      rs += __shfl_xor(rs, 16);
      rs += __shfl_xor(rs, 32);
      l_i = l_i * alpha + rs;

      // rescale O (O layout: col=l15=hd, row=q4*4+r=q) — broadcast alpha per q
#pragma unroll
      for (int r = 0; r < 4; r++) {
        float ar = __shfl(alpha, q4 * 4 + r);
        o_acc[0][r] *= ar; o_acc[1][r] *= ar; o_acc[2][r] *= ar; o_acc[3][r] *= ar;
      }

      // P^T regs -> Ps[q][key] row-major, packed cvt + b64 (4 consecutive keys per quad)
#pragma unroll
      for (int nt = 0; nt < 8; nt++) {
        bf16x4 pk = __builtin_convertvector(sc[nt], bf16x4);
        *(bf16x4*)(&Ps[w][l15 * 136 + nt * 16 + q4 * 4]) = pk;
      }
      __threadfence_block();                        // wave-local LDS write->read ordering

      // O += P V : A = Ps (m=q), B = Vt (n=hd)
#pragma unroll
      for (int ks = 0; ks < 4; ks++) {
        bf16x8 ap = *(const bf16x8*)(&Ps[w][l15 * 136 + ks * 32 + q4 * 8]);
#pragma unroll
        for (int nt2 = 0; nt2 < 4; nt2++) {
          bf16x8 bv = *(const bf16x8*)(Vt + (nt2 * 16 + l15) * 136 + ks * 32 + q4 * 8);
          o_acc[nt2] = __builtin_amdgcn_mfma_f32_16x16x32_bf16(ap, bv, o_acc[nt2], 0, 0, 0);
        }
      }
    }

    // epilogue: O[q=q4*4+r][hd=nt2*16+l15] / l[q] -> bf16 [B,S,D]
#pragma unroll
    for (int r = 0; r < 4; r++) {
      float lr = __shfl(l_i, q4 * 4 + r);
      float inv = 1.0f / lr;
      int s = q0 + w * 16 + q4 * 4 + r;
#pragma unroll
      for (int nt2 = 0; nt2 < 4; nt2++)
        O[((size_t)(b * S_ + s)) * D_ + h * HD_ + nt2 * 16 + l15] = f2b(o_acc[nt2][r] * inv);
    }
  }
}

// ---------------------------------------------------------------- output GEMM
// Same 512-thread 2x4-wave shape as qkv (acc[4][2]); BK=32 dbuf, one barrier/iter; fp32 out.
__global__ __launch_bounds__(512) void out_gemm_kernel(
    const unsigned short* __restrict__ ab, const unsigned short* __restrict__ wot,
    const float* __restrict__ bo, float* __restrict__ out) {
  __shared__ __align__(16) unsigned short smem[4 * 128 * 32];
  const int tid = threadIdx.x;
  const int lane = tid & 63, wid = tid >> 6;
  const int wm = wid & 1, wn = wid >> 1;
  const int m0 = blockIdx.x * 128, n0 = blockIdx.y * 128;
  const int l15 = lane & 15, q4 = lane >> 4;
  const int srow = tid >> 2, skc = (tid & 3) * 8;

  f32x4 zero = {0.f, 0.f, 0.f, 0.f};
  f32x4 acc[4][2];
#pragma unroll
  for (int mt = 0; mt < 4; mt++)
#pragma unroll
    for (int nt = 0; nt < 2; nt++) acc[mt][nt] = zero;

  gl_lds16(ab  + (size_t)(m0 + srow) * D_ + skc, smem + tid * 8);
  gl_lds16(wot + (size_t)(n0 + srow) * D_ + skc, smem + 8192 + tid * 8);

  int ib = 0;
  for (int kk = 0; kk < D_; kk += 32, ib ^= 1) {
    unsigned short* Ab = smem + ib * 4096;
    unsigned short* Bb = smem + 8192 + ib * 4096;
    unsigned short* An = smem + (ib ^ 1) * 4096;
    unsigned short* Bn = smem + 8192 + (ib ^ 1) * 4096;
    __syncthreads();
    if (kk + 32 < D_) {
      gl_lds16(ab  + (size_t)(m0 + srow) * D_ + kk + 32 + skc, An + tid * 8);
      gl_lds16(wot + (size_t)(n0 + srow) * D_ + kk + 32 + skc, Bn + tid * 8);
    }
    bf16x8 af[4], bfv[2];
#pragma unroll
    for (int mt = 0; mt < 4; mt++) af[mt]  = *(const bf16x8*)(Ab + (wm * 64 + mt * 16 + l15) * 32 + q4 * 8);
#pragma unroll
    for (int nt = 0; nt < 2; nt++) bfv[nt] = *(const bf16x8*)(Bb + (wn * 32 + nt * 16 + l15) * 32 + q4 * 8);
#pragma unroll
    for (int mt = 0; mt < 4; mt++)
#pragma unroll
      for (int nt = 0; nt < 2; nt++)
        acc[mt][nt] = __builtin_amdgcn_mfma_f32_16x16x32_bf16(af[mt], bfv[nt], acc[mt][nt], 0, 0, 0);
  }

#pragma unroll
  for (int nt = 0; nt < 2; nt++) {
    int n = n0 + wn * 32 + nt * 16 + l15;
    float bn = bo[n];
#pragma unroll
    for (int mt = 0; mt < 4; mt++) {
#pragma unroll
      for (int r = 0; r < 4; r++) {
        int m = m0 + wm * 64 + mt * 16 + q4 * 4 + r;
        out[(size_t)m * D_ + n] = acc[mt][nt][r] + bn;
      }
    }
  }
}

// ---------------------------------------------------------------- launch
extern "C" void kernel_launch(void* const* d_in, const int* in_sizes, int n_in,
                              void* d_out, int out_size, void* d_ws, size_t ws_size,
                              hipStream_t stream) {
  const float* x  = (const float*)d_in[0];
  const float* wq = (const float*)d_in[1];
  const float* bq = (const float*)d_in[2];
  const float* wk = (const float*)d_in[3];
  const float* bk = (const float*)d_in[4];
  const float* wv = (const float*)d_in[5];
  const float* bv = (const float*)d_in[6];
  const float* wo = (const float*)d_in[7];
  const float* bo = (const float*)d_in[8];
  float* out = (float*)d_out;

  char* ws = (char*)d_ws;
  unsigned short* xb  = (unsigned short*)(ws);               // 8 MB; reused as attn out
  unsigned short* wqt = (unsigned short*)(ws + (8u  << 20));
  unsigned short* wkt = (unsigned short*)(ws + (10u << 20));
  unsigned short* wvt = (unsigned short*)(ws + (12u << 20));
  unsigned short* wot = (unsigned short*)(ws + (14u << 20));
  unsigned short* qb  = (unsigned short*)(ws + (16u << 20)); // [B,H,S,HD] bf16 (pre-scaled)
  unsigned short* kb  = (unsigned short*)(ws + (24u << 20)); // [B,H,S,HD] bf16
  unsigned short* vtg = (unsigned short*)(ws + (32u << 20)); // [B,H,HD,S] bf16 (transposed V)
  unsigned short* ab  = xb;                                  // attention output [B,S,D] bf16

  cvt_all_kernel<<<dim3(32, 32, 5), dim3(32, 8), 0, stream>>>(x, wq, wk, wv, wo, xb, wqt, wkt, wvt, wot);
  qkv_gemm_kernel<<<dim3(32, 8, 3), dim3(512), 0, stream>>>(xb, wqt, wkt, wvt, bq, bk, bv, qb, kb, vtg);
  attn_kernel<<<dim3(8, B_ * H_), dim3(512), 0, stream>>>(qb, kb, vtg, ab);
  out_gemm_kernel<<<dim3(32, 8), dim3(512), 0, stream>>>(ab, wot, bo, out);
}

// Round 10
// 178.659 us; speedup vs baseline: 1.0539x; 1.0539x over previous
//
#include <hip/hip_runtime.h>
#include <hip/hip_bf16.h>
#include <cstdint>

#define B_  2
#define S_  2048
#define D_  1024
#define H_  16
#define HD_ 64
#define M_  (B_ * S_)   // 4096
static constexpr float SC_LOG2E = 0.125f * 1.44269504088896f;  // SCALE * log2(e), folded into Q

typedef __bf16 bf16x8 __attribute__((ext_vector_type(8)));
typedef __bf16 bf16x4 __attribute__((ext_vector_type(4)));
typedef float  f32x4  __attribute__((ext_vector_type(4)));

__device__ __forceinline__ unsigned short f2b(float f) {
  union { float f; unsigned u; } x; x.f = f;
  unsigned r = x.u + 0x7FFF + ((x.u >> 16) & 1);   // RNE
  return (unsigned short)(r >> 16);
}

// async global->LDS, 16B per lane; HW uses wave-uniform LDS base + lane*16
__device__ __forceinline__ void gl_lds16(const unsigned short* g, unsigned short* l) {
  __builtin_amdgcn_global_load_lds((const __attribute__((address_space(1))) void*)g,
                                   (__attribute__((address_space(3))) void*)l, 16, 0, 0);
}

// Barriers that do NOT drain vmcnt(0) (unlike __syncthreads) — keep global loads in flight.
__device__ __forceinline__ void bar_lgkm() {   // LDS-producer barrier (ds_write staging)
  asm volatile("s_waitcnt lgkmcnt(0)\n\ts_barrier" ::: "memory");
}
__device__ __forceinline__ void bar_vm2() {    // retire all but 2 newest vmem (AITER-style)
  asm volatile("s_waitcnt vmcnt(2) lgkmcnt(0)\n\ts_barrier" ::: "memory");
}
__device__ __forceinline__ void bar_vm0() {    // full drain (last iteration)
  asm volatile("s_waitcnt vmcnt(0) lgkmcnt(0)\n\ts_barrier" ::: "memory");
}

// ------------------------------------------- fused cvt: z<4 -> transpose+cvt W, z==4 -> cvt x
__global__ void cvt_all_kernel(const float* __restrict__ x,
                               const float* __restrict__ w0, const float* __restrict__ w1,
                               const float* __restrict__ w2, const float* __restrict__ w3,
                               unsigned short* __restrict__ xb,
                               unsigned short* __restrict__ o0, unsigned short* __restrict__ o1,
                               unsigned short* __restrict__ o2, unsigned short* __restrict__ o3) {
  int tx = threadIdx.x, ty = threadIdx.y;
  if (blockIdx.z == 4) {
    int tid = ty * 32 + tx;
    int base = ((int)blockIdx.y * 32 + (int)blockIdx.x) * 1024 + tid;  // f4 index
    const float4* xf = (const float4*)x;
    ushort4* ob = (ushort4*)xb;
#pragma unroll
    for (int j = 0; j < 4; j++) {
      float4 v = xf[base + j * 256];
      ushort4 r;
      r.x = f2b(v.x); r.y = f2b(v.y); r.z = f2b(v.z); r.w = f2b(v.w);
      ob[base + j * 256] = r;
    }
    return;
  }
  const float* w = blockIdx.z == 0 ? w0 : blockIdx.z == 1 ? w1 : blockIdx.z == 2 ? w2 : w3;
  unsigned short* o = blockIdx.z == 0 ? o0 : blockIdx.z == 1 ? o1 : blockIdx.z == 2 ? o2 : o3;
  __shared__ float t[32][33];
  int x0 = blockIdx.x * 32, y0 = blockIdx.y * 32;
#pragma unroll
  for (int j = 0; j < 4; j++)
    t[ty + j * 8][tx] = w[(size_t)(y0 + ty + j * 8) * D_ + x0 + tx];
  __syncthreads();
#pragma unroll
  for (int j = 0; j < 4; j++)
    o[(size_t)(x0 + ty + j * 8) * D_ + y0 + tx] = f2b(t[tx][ty + j * 8]);
}

// ---------------------------------------------------------------- QKV GEMM
// 512 threads = 8 waves (2x4 wave grid, wave tile 64x32); 128x128 block tile, BK=32.
// TRIPLE-buffered global_load_lds staging; barrier = s_waitcnt vmcnt(2) (not 0!) so the
// in-flight batch for iter+1 stays in flight across the barrier — loads get ~2 compute
// phases to cover HBM latency. Exactly 2 vmem insts per iter per wave => vmcnt(2) retires
// precisely the batch for the buffer about to be computed.
__global__ __launch_bounds__(512) void qkv_gemm_kernel(
    const unsigned short* __restrict__ xb,
    const unsigned short* __restrict__ wqt, const unsigned short* __restrict__ wkt,
    const unsigned short* __restrict__ wvt,
    const float* __restrict__ bq, const float* __restrict__ bk, const float* __restrict__ bv,
    unsigned short* __restrict__ qo, unsigned short* __restrict__ ko, unsigned short* __restrict__ vo) {
  const unsigned short* wt = blockIdx.z == 0 ? wqt : blockIdx.z == 1 ? wkt : wvt;
  const float* bias        = blockIdx.z == 0 ? bq  : blockIdx.z == 1 ? bk  : bv;
  unsigned short* out      = blockIdx.z == 0 ? qo  : blockIdx.z == 1 ? ko  : vo;
  const float scl = blockIdx.z == 0 ? SC_LOG2E : 1.0f;

  // A0|A1|A2|B0|B1|B2, each 128x32 bf16 (4096 shorts); offsets only (no LDS ptr arrays).
  __shared__ __align__(16) unsigned short smem[6 * 4096];   // 48 KB
  const int tid = threadIdx.x;
  const int lane = tid & 63, wid = tid >> 6;
  const int wm = wid & 1, wn = wid >> 1;          // 2 x 4 wave grid
  const int m0 = blockIdx.x * 128, n0 = blockIdx.y * 128;
  const int l15 = lane & 15, q4 = lane >> 4;
  const int srow = tid >> 2, skc = (tid & 3) * 8; // staging slot: 512 chunks, 1/thread

  f32x4 zero = {0.f, 0.f, 0.f, 0.f};
  f32x4 acc[4][2];
#pragma unroll
  for (int mt = 0; mt < 4; mt++)
#pragma unroll
    for (int nt = 0; nt < 2; nt++) acc[mt][nt] = zero;

  const unsigned short* ap = xb + (size_t)(m0 + srow) * D_ + skc;
  const unsigned short* bp = wt + (size_t)(n0 + srow) * D_ + skc;
  // preload batches 0,1 into bufs 0,1 (4 vmem in flight)
  gl_lds16(ap,      smem + tid * 8);
  gl_lds16(bp,      smem + 12288 + tid * 8);
  gl_lds16(ap + 32, smem + 4096 + tid * 8);
  gl_lds16(bp + 32, smem + 12288 + 4096 + tid * 8);

  int bc = 0;                                      // current buffer = it % 3
  for (int it = 0; it < 32; it++) {
    if (it < 31) bar_vm2(); else bar_vm0();        // retire batch `it`; keep batch it+1 flying
    if (it + 2 < 32) {
      int bn_ = bc < 1 ? bc + 2 : bc - 1;          // (it+2) % 3
      gl_lds16(ap + (it + 2) * 32, smem + bn_ * 4096 + tid * 8);
      gl_lds16(bp + (it + 2) * 32, smem + 12288 + bn_ * 4096 + tid * 8);
    }
    const unsigned short* Ab = smem + bc * 4096;
    const unsigned short* Bb = smem + 12288 + bc * 4096;
    bf16x8 af[4], bfv[2];
#pragma unroll
    for (int mt = 0; mt < 4; mt++) af[mt]  = *(const bf16x8*)(Ab + (wm * 64 + mt * 16 + l15) * 32 + q4 * 8);
#pragma unroll
    for (int nt = 0; nt < 2; nt++) bfv[nt] = *(const bf16x8*)(Bb + (wn * 32 + nt * 16 + l15) * 32 + q4 * 8);
#pragma unroll
    for (int mt = 0; mt < 4; mt++)
#pragma unroll
      for (int nt = 0; nt < 2; nt++)
        acc[mt][nt] = __builtin_amdgcn_mfma_f32_16x16x32_bf16(af[mt], bfv[nt], acc[mt][nt], 0, 0, 0);
    bc = bc == 2 ? 0 : bc + 1;
  }

  if (blockIdx.z < 2) {
    // Q/K: store [B,H,S,HD]
#pragma unroll
    for (int nt = 0; nt < 2; nt++) {
      int n = n0 + wn * 32 + nt * 16 + l15;
      float bn = bias[n];
      int h = n >> 6, hd = n & 63;
#pragma unroll
      for (int mt = 0; mt < 4; mt++) {
#pragma unroll
        for (int r = 0; r < 4; r++) {
          int m = m0 + wm * 64 + mt * 16 + q4 * 4 + r;   // C row = quad*4 + reg
          int b = m >> 11, s = m & (S_ - 1);
          out[(((size_t)(b * H_ + h)) * S_ + s) * HD_ + hd] = f2b((acc[mt][nt][r] + bn) * scl);
        }
      }
    }
  } else {
    // V: transpose via LDS (64x136 pad), store [B,H,HD,S] coalesced; packed b64 writes
    unsigned short* buf = smem;                         // 8704 shorts < 24576
#pragma unroll
    for (int p = 0; p < 2; p++) {                       // n-half: wn in {2p, 2p+1}
      __syncthreads();
      if ((wn >> 1) == p) {
#pragma unroll
        for (int nt = 0; nt < 2; nt++) {
          int np = (wn & 1) * 32 + nt * 16 + l15;       // n' in [0,64)
          float bn = bias[n0 + p * 64 + np];
#pragma unroll
          for (int mt = 0; mt < 4; mt++) {
            f32x4 vb = acc[mt][nt];
            vb[0] += bn; vb[1] += bn; vb[2] += bn; vb[3] += bn;
            bf16x4 pk = __builtin_convertvector(vb, bf16x4);
            *(bf16x4*)(&buf[np * 136 + wm * 64 + mt * 16 + q4 * 4]) = pk;
          }
        }
      }
      __syncthreads();
#pragma unroll
      for (int i = 0; i < 2; i++) {
        int ci = tid + i * 512;                      // 1024 chunks of 8
        int np = ci >> 4, c = ci & 15;
        int n = n0 + p * 64 + np;
        int h = n >> 6, hd = n & 63;
        int m = m0 + c * 8;
        int b = m >> 11, s = m & (S_ - 1);
        *(uint4*)(out + (((size_t)(b * H_ + h)) * HD_ + hd) * S_ + s) = *(const uint4*)(buf + np * 136 + c * 8);
      }
    }
  }
}

// ---------------------------------------------------------------- flash attention (S^T form)
// grid (8, B*H); 8 waves, 128 q-rows; block x does q-tiles {x, 15-x} (17 k-tiles, uniform).
// K/V double-buffered in LDS, ONE barrier/tile — but the barrier waits ONLY lgkmcnt
// (staging is regs->ds_write; the reg prefetch global loads stay in flight across it and
// are waited per-wave at their ds_write use, not block-wide). tc carries buffer parity
// across halves. Q frags direct from global once per half.
__global__ __launch_bounds__(512) void attn_kernel(
    const unsigned short* __restrict__ Q, const unsigned short* __restrict__ K,
    const unsigned short* __restrict__ Vt_g, unsigned short* __restrict__ O) {
  const int bh = blockIdx.y, b = bh >> 4, h = bh & 15;
  const unsigned short* Qh = Q    + (size_t)bh * S_ * HD_;
  const unsigned short* Kh = K    + (size_t)bh * S_ * HD_;
  const unsigned short* Vh = Vt_g + (size_t)bh * HD_ * S_;   // [HD][S]

  __shared__ __align__(16) unsigned short Ks[2][128 * 72];   // [key][hd], pad 72
  __shared__ __align__(16) unsigned short Vt[2][64 * 136];   // [hd][key], pad 136
  __shared__ __align__(16) unsigned short Ps[8][16 * 136];   // per-wave P [q][key]

  const int tid = threadIdx.x, lane = tid & 63, w = tid >> 6;
  const int l15 = lane & 15, q4 = lane >> 4;
  f32x4 zero = {0.f, 0.f, 0.f, 0.f};

  const int krow0 = tid >> 3, kcol0 = (tid & 7) * 8;          // K stage slots (this thread)
  const int vrow0 = tid >> 4, vcol0 = (tid & 15) * 8;         // Vt stage slots

  int tc = 0;                                                 // running tile counter (parity)
  for (int half = 0; half < 2; half++) {
    const int qi = half ? (15 - (int)blockIdx.x) : (int)blockIdx.x;
    const int q0 = qi * 128;

    // Q B-frags direct from global: B[k=q4*8+j][n=l15] = Q[q0+w*16+l15][q4*8+j]
    const unsigned short* qp = Qh + (size_t)(q0 + w * 16 + l15) * HD_ + q4 * 8;
    bf16x8 bq0 = *(const bf16x8*)(qp);
    bf16x8 bq1 = *(const bf16x8*)(qp + 32);

    float m_i = -1e30f, l_i = 0.f;                 // state for q = q0 + w*16 + l15
    f32x4 o_acc[4];
#pragma unroll
    for (int t = 0; t < 4; t++) o_acc[t] = zero;
    const int qrow = q0 + w * 16 + l15;
    const int nkt = qi + 1;

    // prefetch tile 0 into regs
    uint4 kp0 = *(const uint4*)(Kh + (size_t)krow0 * HD_ + kcol0);
    uint4 kp1 = *(const uint4*)(Kh + (size_t)(krow0 + 64) * HD_ + kcol0);
    uint4 vp0 = *(const uint4*)(Vh + (size_t)vrow0 * S_ + vcol0);
    uint4 vp1 = *(const uint4*)(Vh + (size_t)(vrow0 + 32) * S_ + vcol0);

    for (int kt = 0; kt < nkt; kt++, tc++) {
      const int k0 = kt * 128;
      const int bi = tc & 1;
      unsigned short* Kb = Ks[bi];
      unsigned short* Vb = Vt[bi];
      // stage tile kt (regs were loaded during previous tile's compute)
      *(uint4*)(Kb + krow0 * 72 + kcol0) = kp0;
      *(uint4*)(Kb + (krow0 + 64) * 72 + kcol0) = kp1;
      *(uint4*)(Vb + vrow0 * 136 + vcol0) = vp0;
      *(uint4*)(Vb + (vrow0 + 32) * 136 + vcol0) = vp1;
      bar_lgkm();                                  // barrier WITHOUT vmcnt drain
      if (kt + 1 < nkt) {                          // next-tile loads: in flight across barriers
        int kn = k0 + 128;
        kp0 = *(const uint4*)(Kh + (size_t)(kn + krow0) * HD_ + kcol0);
        kp1 = *(const uint4*)(Kh + (size_t)(kn + krow0 + 64) * HD_ + kcol0);
        vp0 = *(const uint4*)(Vh + (size_t)vrow0 * S_ + kn + vcol0);
        vp1 = *(const uint4*)(Vh + (size_t)(vrow0 + 32) * S_ + kn + vcol0);
      }

      // S^T = K·Q^T : A = K-frag (m=key), B = Q-frag (n=q); Q pre-scaled by SC_LOG2E
      f32x4 sc[8];
#pragma unroll
      for (int nt = 0; nt < 8; nt++) sc[nt] = zero;
#pragma unroll
      for (int nt = 0; nt < 8; nt++) {
        bf16x8 ak0 = *(const bf16x8*)(Kb + (nt * 16 + l15) * 72 + q4 * 8);
        bf16x8 ak1 = *(const bf16x8*)(Kb + (nt * 16 + l15) * 72 + 32 + q4 * 8);
        sc[nt] = __builtin_amdgcn_mfma_f32_16x16x32_bf16(ak0, bq0, sc[nt], 0, 0, 0);
        sc[nt] = __builtin_amdgcn_mfma_f32_16x16x32_bf16(ak1, bq1, sc[nt], 0, 0, 0);
      }

      // softmax over keys for q = l15 (C layout: col=l15=q, row=q4*4+r=key), log2 domain
      const bool needMask = (k0 + 127) > (q0 + w * 16);
      float mx = m_i;
      if (needMask) {
#pragma unroll
        for (int nt = 0; nt < 8; nt++)
#pragma unroll
          for (int r = 0; r < 4; r++) {
            int key = k0 + nt * 16 + q4 * 4 + r;
            float v = (key > qrow) ? -1e30f : sc[nt][r];
            sc[nt][r] = v;
            mx = fmaxf(mx, v);
          }
      } else {
#pragma unroll
        for (int nt = 0; nt < 8; nt++)
#pragma unroll
          for (int r = 0; r < 4; r++) mx = fmaxf(mx, sc[nt][r]);
      }
      mx = fmaxf(mx, __shfl_xor(mx, 16));
      mx = fmaxf(mx, __shfl_xor(mx, 32));
      float alpha = __builtin_amdgcn_exp2f(m_i - mx);
      m_i = mx;
      float rs = 0.f;
#pragma unroll
      for (int nt = 0; nt < 8; nt++)
#pragma unroll
        for (int r = 0; r < 4; r++) {
          float p = __builtin_amdgcn_exp2f(sc[nt][r] - mx);
          sc[nt][r] = p;
          rs += p;
        }
      rs += __shfl_xor(rs, 16);
      rs += __shfl_xor(rs, 32);
      l_i = l_i * alpha + rs;

      // rescale O (O layout: col=l15=hd, row=q4*4+r=q) — broadcast alpha per q
#pragma unroll
      for (int r = 0; r < 4; r++) {
        float ar = __shfl(alpha, q4 * 4 + r);
        o_acc[0][r] *= ar; o_acc[1][r] *= ar; o_acc[2][r] *= ar; o_acc[3][r] *= ar;
      }

      // P^T regs -> Ps[q][key] row-major, packed cvt + b64 (4 consecutive keys per quad)
#pragma unroll
      for (int nt = 0; nt < 8; nt++) {
        bf16x4 pk = __builtin_convertvector(sc[nt], bf16x4);
        *(bf16x4*)(&Ps[w][l15 * 136 + nt * 16 + q4 * 4]) = pk;
      }
      __threadfence_block();                        // wave-local LDS write->read ordering

      // O += P V : A = Ps (m=q), B = Vt (n=hd)
#pragma unroll
      for (int ks = 0; ks < 4; ks++) {
        bf16x8 ap = *(const bf16x8*)(&Ps[w][l15 * 136 + ks * 32 + q4 * 8]);
#pragma unroll
        for (int nt2 = 0; nt2 < 4; nt2++) {
          bf16x8 bv = *(const bf16x8*)(Vb + (nt2 * 16 + l15) * 136 + ks * 32 + q4 * 8);
          o_acc[nt2] = __builtin_amdgcn_mfma_f32_16x16x32_bf16(ap, bv, o_acc[nt2], 0, 0, 0);
        }
      }
    }

    // epilogue: O[q=q4*4+r][hd=nt2*16+l15] / l[q] -> bf16 [B,S,D]
#pragma unroll
    for (int r = 0; r < 4; r++) {
      float lr = __shfl(l_i, q4 * 4 + r);
      float inv = 1.0f / lr;
      int s = q0 + w * 16 + q4 * 4 + r;
#pragma unroll
      for (int nt2 = 0; nt2 < 4; nt2++)
        O[((size_t)(b * S_ + s)) * D_ + h * HD_ + nt2 * 16 + l15] = f2b(o_acc[nt2][r] * inv);
    }
  }
}

// ---------------------------------------------------------------- output GEMM
// Same 512-thread shape as qkv; triple-buffer + vmcnt(2) barriers; fp32 out.
__global__ __launch_bounds__(512) void out_gemm_kernel(
    const unsigned short* __restrict__ ab, const unsigned short* __restrict__ wot,
    const float* __restrict__ bo, float* __restrict__ out) {
  __shared__ __align__(16) unsigned short smem[6 * 4096];   // 48 KB
  const int tid = threadIdx.x;
  const int lane = tid & 63, wid = tid >> 6;
  const int wm = wid & 1, wn = wid >> 1;
  const int m0 = blockIdx.x * 128, n0 = blockIdx.y * 128;
  const int l15 = lane & 15, q4 = lane >> 4;
  const int srow = tid >> 2, skc = (tid & 3) * 8;

  f32x4 zero = {0.f, 0.f, 0.f, 0.f};
  f32x4 acc[4][2];
#pragma unroll
  for (int mt = 0; mt < 4; mt++)
#pragma unroll
    for (int nt = 0; nt < 2; nt++) acc[mt][nt] = zero;

  const unsigned short* ap = ab  + (size_t)(m0 + srow) * D_ + skc;
  const unsigned short* bp = wot + (size_t)(n0 + srow) * D_ + skc;
  gl_lds16(ap,      smem + tid * 8);
  gl_lds16(bp,      smem + 12288 + tid * 8);
  gl_lds16(ap + 32, smem + 4096 + tid * 8);
  gl_lds16(bp + 32, smem + 12288 + 4096 + tid * 8);

  int bc = 0;
  for (int it = 0; it < 32; it++) {
    if (it < 31) bar_vm2(); else bar_vm0();
    if (it + 2 < 32) {
      int bn_ = bc < 1 ? bc + 2 : bc - 1;
      gl_lds16(ap + (it + 2) * 32, smem + bn_ * 4096 + tid * 8);
      gl_lds16(bp + (it + 2) * 32, smem + 12288 + bn_ * 4096 + tid * 8);
    }
    const unsigned short* Ab = smem + bc * 4096;
    const unsigned short* Bb = smem + 12288 + bc * 4096;
    bf16x8 af[4], bfv[2];
#pragma unroll
    for (int mt = 0; mt < 4; mt++) af[mt]  = *(const bf16x8*)(Ab + (wm * 64 + mt * 16 + l15) * 32 + q4 * 8);
#pragma unroll
    for (int nt = 0; nt < 2; nt++) bfv[nt] = *(const bf16x8*)(Bb + (wn * 32 + nt * 16 + l15) * 32 + q4 * 8);
#pragma unroll
    for (int mt = 0; mt < 4; mt++)
#pragma unroll
      for (int nt = 0; nt < 2; nt++)
        acc[mt][nt] = __builtin_amdgcn_mfma_f32_16x16x32_bf16(af[mt], bfv[nt], acc[mt][nt], 0, 0, 0);
    bc = bc == 2 ? 0 : bc + 1;
  }

#pragma unroll
  for (int nt = 0; nt < 2; nt++) {
    int n = n0 + wn * 32 + nt * 16 + l15;
    float bn = bo[n];
#pragma unroll
    for (int mt = 0; mt < 4; mt++) {
#pragma unroll
      for (int r = 0; r < 4; r++) {
        int m = m0 + wm * 64 + mt * 16 + q4 * 4 + r;
        out[(size_t)m * D_ + n] = acc[mt][nt][r] + bn;
      }
    }
  }
}

// ---------------------------------------------------------------- launch
extern "C" void kernel_launch(void* const* d_in, const int* in_sizes, int n_in,
                              void* d_out, int out_size, void* d_ws, size_t ws_size,
                              hipStream_t stream) {
  const float* x  = (const float*)d_in[0];
  const float* wq = (const float*)d_in[1];
  const float* bq = (const float*)d_in[2];
  const float* wk = (const float*)d_in[3];
  const float* bk = (const float*)d_in[4];
  const float* wv = (const float*)d_in[5];
  const float* bv = (const float*)d_in[6];
  const float* wo = (const float*)d_in[7];
  const float* bo = (const float*)d_in[8];
  float* out = (float*)d_out;

  char* ws = (char*)d_ws;
  unsigned short* xb  = (unsigned short*)(ws);               // 8 MB; reused as attn out
  unsigned short* wqt = (unsigned short*)(ws + (8u  << 20));
  unsigned short* wkt = (unsigned short*)(ws + (10u << 20));
  unsigned short* wvt = (unsigned short*)(ws + (12u << 20));
  unsigned short* wot = (unsigned short*)(ws + (14u << 20));
  unsigned short* qb  = (unsigned short*)(ws + (16u << 20)); // [B,H,S,HD] bf16 (pre-scaled)
  unsigned short* kb  = (unsigned short*)(ws + (24u << 20)); // [B,H,S,HD] bf16
  unsigned short* vtg = (unsigned short*)(ws + (32u << 20)); // [B,H,HD,S] bf16 (transposed V)
  unsigned short* ab  = xb;                                  // attention output [B,S,D] bf16

  cvt_all_kernel<<<dim3(32, 32, 5), dim3(32, 8), 0, stream>>>(x, wq, wk, wv, wo, xb, wqt, wkt, wvt, wot);
  qkv_gemm_kernel<<<dim3(32, 8, 3), dim3(512), 0, stream>>>(xb, wqt, wkt, wvt, bq, bk, bv, qb, kb, vtg);
  attn_kernel<<<dim3(8, B_ * H_), dim3(512), 0, stream>>>(qb, kb, vtg, ab);
  out_gemm_kernel<<<dim3(32, 8), dim3(512), 0, stream>>>(ab, wot, bo, out);
}